// Round 10
// baseline (86.742 us; speedup 1.0000x reference)
//
#include <hip/hip_runtime.h>
#include <math.h>

// Contour-to-distance-map, round 10.
// R9 neutral -> branch count was not the constant. 9-round model: op removals
// pay 1:1, but a ~130cy/WAVE-step constant survives everything except
// pixel-ILP (R3: ILP-2 won 1.26x). So: ILP-4 pixels per lane (each wave-step
// serves 4 pixels), block = 4 waves x same 256 pixels, 4-way edge split,
// grid 576x256 (147456=576*256 -> no bounds checks). __any can't survive
// ILP-4 (1280 trials/group -> always taken) -> correction fully branchless:
//   wcorr += (1-t)*copysign(pi,-crz)*[dot<0],  (1-t)=2e/(1+e) exact.
// pi-for-atan error <= 3.7e-6/|dot| rad; small-|dot| cases are
// vertex-adjacent -> damped by min_diff. |crz|>=9e-5 -> correction exactly 0.

#define INV_2PI 0.15915494309189535f
#define TWO_PI  6.28318530717958648f
#define PI_F    3.14159265358979323846f
#define KK2     200000.0f             // 2*k

__global__ void prep_kernel(const float2* __restrict__ contour,
                            float2* __restrict__ ext, int N, int L) {
    const int t = blockIdx.x * blockDim.x + threadIdx.x;
    if (t < L) ext[t] = contour[(t < N) ? t : 0];
}

struct Ch { float dx, dy, minn, wind, wcorr; };

__device__ __forceinline__ void ch_init(Ch& c, float vx, float vy,
                                        float px, float py) {
    c.dx = vx - px;
    c.dy = vy - py;
    c.minn = fmaf(c.dx, c.dx, c.dy * c.dy);
    c.wind = 0.0f;
    c.wcorr = 0.0f;
}

__device__ __forceinline__ void ch_step(Ch& c, float vx, float vy,
                                        float px, float py) {
    const float dxn = vx - px;
    const float dyn = vy - py;
    const float d2  = fmaf(dxn, dxn, dyn * dyn);
    c.minn = fminf(c.minn, d2);

    const float crz = fmaf(c.dx, dyn, -(c.dy * dxn)); // ref cross == -crz
    const float dot = fmaf(c.dx, dxn, c.dy * dyn);

    // half-open ray crossing (identical predicates to R8/R9, which passed)
    const bool pc = (c.dy <= 0.0f);
    const bool pn = (dyn  <= 0.0f);
    float inc = (pc & !pn & (crz > 0.0f)) ?  1.0f : 0.0f;
    inc       = (!pc & pn & (crz < 0.0f)) ? -1.0f : inc;
    c.wind += inc;

    // branchless tanh-weight correction:
    // (1-t) = 2e/(1+e), e = exp(-2k|crz|); exactly 0 for |crz|>=9e-5
    const float ay  = fabsf(crz);
    const float e   = __expf(ay * -KK2);
    const float omt = (e + e) * __builtin_amdgcn_rcpf(1.0f + e);
    const float g   = (dot < 0.0f) ? copysignf(PI_F, -crz) : 0.0f;
    c.wcorr = fmaf(omt, g, c.wcorr);

    c.dx = dxn; c.dy = dyn;
}

__global__ void __launch_bounds__(256, 3)
winding_kernel(const float2* __restrict__ ext, int Q, int S, float invS,
               float* __restrict__ out, float* __restrict__ bmax) {
    __shared__ float s_w[4][256];
    __shared__ float s_m[4][256];
    __shared__ float s_red[4];

    const int tid  = threadIdx.x;
    const int lane = tid & 63;
    const int wid  = __builtin_amdgcn_readfirstlane(tid >> 6);

    const int pixBase = blockIdx.x * 256;     // block covers 256 pixels
    const int base    = wid * Q;              // this wave's edge range (scalar)

    // 4 pixel chains per lane: pixels pixBase + 64*c + lane
    float pxv[4], pyv[4];
    #pragma unroll
    for (int c = 0; c < 4; ++c) {
        const int p = pixBase + 64 * c + lane;
        const int i = p / S, j = p - i * S;
        pxv[c] = (float)i * invS;
        pyv[c] = (float)j * invS;
    }

    const float2 v0 = ext[base];
    Ch ch[4];
    #pragma unroll
    for (int c = 0; c < 4; ++c) ch_init(ch[c], v0.x, v0.y, pxv[c], pyv[c]);

    #pragma unroll 5
    for (int k = 1; k <= Q; ++k) {
        const float2 v = ext[base + k];       // scalar load
        #pragma unroll
        for (int c = 0; c < 4; ++c) ch_step(ch[c], v.x, v.y, pxv[c], pyv[c]);
    }

    #pragma unroll
    for (int c = 0; c < 4; ++c) {
        const int idx = 64 * c + lane;
        s_w[wid][idx] = fmaf(-TWO_PI, ch[c].wind, -ch[c].wcorr);
        s_m[wid][idx] = ch[c].minn;
    }
    __syncthreads();

    // each thread finalizes one pixel (tid in 0..255)
    const float wt = (s_w[0][tid] + s_w[1][tid]) + (s_w[2][tid] + s_w[3][tid]);
    const float mt = fminf(fminf(s_m[0][tid], s_m[1][tid]),
                           fminf(s_m[2][tid], s_m[3][tid]));
    const float prod = (wt * INV_2PI) * __builtin_amdgcn_sqrtf(mt);
    out[pixBase + tid] = prod;

    // block max -> bmax[block]
    float v = prod;
    #pragma unroll
    for (int off = 32; off >= 1; off >>= 1)
        v = fmaxf(v, __shfl_down(v, off, 64));
    if (lane == 0) s_red[wid] = v;
    __syncthreads();
    if (tid == 0)
        bmax[blockIdx.x] = fmaxf(fmaxf(s_red[0], s_red[1]),
                                 fmaxf(s_red[2], s_red[3]));
}

__global__ void __launch_bounds__(256)
normalize_kernel(float4* __restrict__ out4, const float* __restrict__ bmax,
                 int nmax, int total4) {
    const int tid  = threadIdx.x;
    const int lane = tid & 63;
    const int wid  = tid >> 6;

    float m = -INFINITY;
    for (int t = tid; t < nmax; t += 256) m = fmaxf(m, bmax[t]);
    #pragma unroll
    for (int off = 32; off >= 1; off >>= 1)
        m = fmaxf(m, __shfl_down(m, off, 64));
    __shared__ float sm[4];
    if (lane == 0) sm[wid] = m;
    __syncthreads();
    m = fmaxf(fmaxf(sm[0], sm[1]), fmaxf(sm[2], sm[3]));
    const float inv = 1.0f / m;

    const int idx = blockIdx.x * 256 + tid;
    if (idx < total4) {
        float4 v = out4[idx];
        v.x *= inv; v.y *= inv; v.z *= inv; v.w *= inv;
        out4[idx] = v;
    }
}

extern "C" void kernel_launch(void* const* d_in, const int* in_sizes, int n_in,
                              void* d_out, int out_size, void* d_ws, size_t ws_size,
                              hipStream_t stream) {
    const float2* contour = (const float2*)d_in[0];
    const int N = in_sizes[0] / 2;                       // 200
    const int S = (int)(sqrt((double)out_size) + 0.5);   // 384
    const float invS = 1.0f / (float)S;
    float* out  = (float*)d_out;
    float* bmax = (float*)d_ws;                          // 576 floats
    float2* ext = (float2*)((char*)d_ws + 16384);        // wrapped contour

    // 4-way edge split: wave w handles edges [wQ, wQ+Q); ext[t]=c[t<N?t:0]
    // pads are c0->c0 edges: crz==0 exactly -> wind 0, dot>0 -> corr 0.
    const int Q = (N + 3) / 4;                           // 50
    const int L = 4 * Q + 1;                             // 201

    prep_kernel<<<(L + 255) / 256, 256, 0, stream>>>(contour, ext, N, L);

    const int total   = S * S;
    const int wblocks = total / 256;                     // 576 (exact)
    winding_kernel<<<wblocks, 256, 0, stream>>>(ext, Q, S, invS, out, bmax);

    const int total4  = total / 4;
    const int nblocks = (total4 + 255) / 256;            // 144
    normalize_kernel<<<nblocks, 256, 0, stream>>>((float4*)out, bmax,
                                                  wblocks, total4);
}